// Round 1
// 209.905 us; speedup vs baseline: 1.0920x; 1.0920x over previous
//
#include <hip/hip_runtime.h>
#include <math.h>

typedef __attribute__((ext_vector_type(4))) float f32x4;
typedef __attribute__((ext_vector_type(8))) short s16x8;

__device__ inline unsigned f2bf(float f) {
    unsigned u = __float_as_uint(f);
    u += 0x7FFFu + ((u >> 16) & 1u);
    return u >> 16;
}
__device__ inline float bflo(unsigned u) { return __uint_as_float(u << 16); }
__device__ inline float bfhi(unsigned u) { return __uint_as_float(u & 0xFFFF0000u); }

// ---------------------------------------------------------------------------
// pack_x: x (2,256,8,32,32) f32 -> xt[n][y][x][c] bf16 channels-last
// ---------------------------------------------------------------------------
__global__ __launch_bounds__(256) void pack_x(const float* __restrict__ x,
                                              unsigned* __restrict__ xt32)
{
    __shared__ float tile[256][33];
    const int tid = threadIdx.x;
    const int n = blockIdx.x >> 5, y = blockIdx.x & 31;
    const int b = n >> 3, ts = n & 7;
    const float* src = x + (((size_t)b * 256 * 8) + ts) * 1024 + y * 32;
    #pragma unroll
    for (int rep = 0; rep < 32; ++rep) {
        int c = rep * 8 + (tid >> 5);
        int w = tid & 31;
        tile[c][w] = src[(size_t)c * 8192 + w];
    }
    __syncthreads();
    unsigned* dst = xt32 + ((size_t)n * 1024 + y * 32) * 128;
    #pragma unroll
    for (int rep = 0; rep < 16; ++rep) {
        int idx = rep * 256 + tid;
        int cp = idx & 127, w = idx >> 7;
        unsigned lo = f2bf(tile[2 * cp][w]);
        unsigned hi = f2bf(tile[2 * cp + 1][w]);
        dst[(size_t)w * 128 + cp] = lo | (hi << 16);
    }
}

// ---------------------------------------------------------------------------
// pack_wo: weight -> Wp[t][o][c] bf16 ; offset_w -> Wo[t][m(pad32)][c] bf16
// ---------------------------------------------------------------------------
__global__ __launch_bounds__(256) void pack_wo(const float* __restrict__ w,
                                               const float* __restrict__ ow,
                                               short* __restrict__ Wp,
                                               short* __restrict__ Wo)
{
    int j = blockIdx.x * 256 + threadIdx.x;
    if (j < 9 * 256 * 256) {
        int c = j & 255, o = (j >> 8) & 255, t = j >> 16;
        Wp[j] = (short)f2bf(w[((size_t)o * 256 + c) * 9 + t]);
    } else {
        int k = j - 9 * 256 * 256;            // < 9*32*256
        int c = k & 255, m = (k >> 8) & 31, t = k >> 13;
        float v = 0.f;
        if (m < 27) v = ow[((size_t)m * 256 + c) * 9 + t];
        Wo[k] = (short)f2bf(v);
    }
}

// ---------------------------------------------------------------------------
// offsets_kernel: MFMA offset-conv + descriptor math -> global descW/descI.
// Block = (n, ho), 4 waves: nt = w&1, half = w>>1 (K-half). (round-2 verified)
// ---------------------------------------------------------------------------
__global__ __launch_bounds__(256) void offsets_kernel(
    const short* __restrict__ xt, const short* __restrict__ Wo,
    const float* __restrict__ ob, float4* __restrict__ descW,
    int4* __restrict__ descI)
{
    __shared__ float pom[2][32][33];
    const int tid = threadIdx.x;
    const int n = blockIdx.x >> 5, ho = blockIdx.x & 31;
    const int lane = tid & 63, wv = tid >> 6;
    const int nt = wv & 1, half = wv >> 1;
    const int l15 = lane & 15, quad = lane >> 4;
    const int pos = nt * 16 + l15;
    const short* xn = xt + (size_t)n * (1024 * 256);
    const s16x8 z8 = {0, 0, 0, 0, 0, 0, 0, 0};

    f32x4 oacc0 = {0, 0, 0, 0}, oacc1 = {0, 0, 0, 0};
    for (int t = 0; t < 9; ++t) {
        int ki = t / 3, kj = t - 3 * ki;
        int y = ho - 1 + ki;
        if (y < 0 || y >= 32) continue;
        int xc = pos - 1 + kj;
        bool vx = (xc >= 0) && (xc < 32);
        int xcl = min(max(xc, 0), 31);
        const short* bp  = xn + (y * 32 + xcl) * 256;
        const short* ap0 = Wo + (t * 32 + l15) * 256;
        #pragma unroll
        for (int cc = 0; cc < 4; ++cc) {
            int c = half * 128 + cc * 32 + quad * 8;
            s16x8 bfrag = *(const s16x8*)(bp + c);
            if (!vx) bfrag = z8;
            s16x8 a0 = *(const s16x8*)(ap0 + c);
            s16x8 a1 = *(const s16x8*)(ap0 + 16 * 256 + c);
            oacc0 = __builtin_amdgcn_mfma_f32_16x16x32_bf16(a0, bfrag, oacc0, 0, 0, 0);
            oacc1 = __builtin_amdgcn_mfma_f32_16x16x32_bf16(a1, bfrag, oacc1, 0, 0, 0);
        }
    }
    #pragma unroll
    for (int r = 0; r < 4; ++r) {
        pom[half][quad * 4 + r][pos]      = oacc0[r];
        pom[half][16 + quad * 4 + r][pos] = oacc1[r];
    }
    __syncthreads();

    for (int s = tid; s < 288; s += 256) {
        int t = s >> 5, wo = s & 31;
        float dy = pom[0][2 * t][wo]     + pom[1][2 * t][wo]     + ob[2 * t];
        float dx = pom[0][2 * t + 1][wo] + pom[1][2 * t + 1][wo] + ob[2 * t + 1];
        float mv = pom[0][18 + t][wo]    + pom[1][18 + t][wo]    + ob[18 + t];
        float mk = 1.0f / (1.0f + __expf(-mv));
        float py = dy + (float)(ho - 1 + t / 3);
        float px = dx + (float)(wo - 1 + t % 3);
        float y0f = floorf(py), x0f = floorf(px);
        float ty = py - y0f, tx = px - x0f;
        int y0 = (int)y0f, x0 = (int)x0f;
        int y1 = y0 + 1, x1 = x0 + 1;
        bool vy0 = (y0 >= 0) && (y0 < 32), vy1 = (y1 >= 0) && (y1 < 32);
        bool vx0 = (x0 >= 0) && (x0 < 32), vx1 = (x1 >= 0) && (x1 < 32);
        int cy0 = min(max(y0, 0), 31), cy1 = min(max(y1, 0), 31);
        int cx0 = min(max(x0, 0), 31), cx1 = min(max(x1, 0), 31);
        float b0 = (1.f - ty) * (1.f - tx) * mk * (float)(vy0 && vx0);
        float b1 = (1.f - ty) * tx         * mk * (float)(vy0 && vx1);
        float b2 = ty * (1.f - tx)         * mk * (float)(vy1 && vx0);
        float b3 = ty * tx                 * mk * (float)(vy1 && vx1);
        size_t base = (size_t)(n * 32 + ho) * 288 + s;
        descW[base] = make_float4(b0, b1, b2, b3);
        descI[base] = make_int4((cy0 * 32 + cx0) * 256, (cy0 * 32 + cx1) * 256,
                                (cy1 * 32 + cx0) * 256, (cy1 * 32 + cx1) * 256);
    }
}

// ---------------------------------------------------------------------------
// init_out: out = bias (f32), vectorized. 4096 blocks.
// ---------------------------------------------------------------------------
__global__ __launch_bounds__(256) void init_out(const float* __restrict__ bias,
                                                float4* __restrict__ out)
{
    int i = blockIdx.x * 256 + threadIdx.x;   // < 1048576
    int oc = (i >> 11) & 255;
    float bv = bias[oc];
    out[i] = make_float4(bv, bv, bv, bv);
}

// ---------------------------------------------------------------------------
// dcn_main: block = (n, ho, kh). 4 waves = oc-quarters, each does both
// n-tiles (A-frag reuse). 18 stages of (64 ch, 1 tap).
// Round-1 changes:
//   (a) gathers for stage s+1 are ISSUED during stage s's MFMA phase
//       (software pipeline; issued AFTER A-frag loads so the compiler's
//       counted vmcnt for the MFMAs leaves them in flight);
//   (b) repack role remapped to oct=tid&7, pos=tid>>3 so each wave's
//       corner-gather covers 8 positions x 128 contiguous B (2x fewer
//       cache-line transactions) and the LDS write is bank-conflict-free.
// Single-barrier dbuf argument unchanged: buffer s&1 written at stage s is
// next written at s+2, after barrier s+1, by which time stage-s reads done.
// ---------------------------------------------------------------------------
__global__ __launch_bounds__(256, 4) void dcn_main(
    const short* __restrict__ xt, const short* __restrict__ Wp,
    const float4* __restrict__ descW, const int4* __restrict__ descI,
    float* __restrict__ out)
{
    __shared__ short  sB[2][32 * 72];    // 32 pos x 64 c (+8 pad), 16B rows
    __shared__ float4 sdw[288];
    __shared__ int4   sdi[288];

    const int tid = threadIdx.x;
    const int bid = blockIdx.x;
    const int kh = bid & 1;
    const int r  = bid >> 1;
    const int n = r >> 5, ho = r & 31;

    // stage descriptors for this (n, ho)
    {
        const float4* dW = descW + (size_t)(n * 32 + ho) * 288;
        const int4*   dI = descI + (size_t)(n * 32 + ho) * 288;
        for (int i = tid; i < 288; i += 256) { sdw[i] = dW[i]; sdi[i] = dI[i]; }
    }
    __syncthreads();

    const int oct = tid & 7, pos = tid >> 3;       // coalesced repack role
    const int oq = tid >> 6;                       // wave = oc-quarter
    const int lane = tid & 63, l15 = lane & 15, quad = lane >> 4;
    const short* xn = xt + (size_t)n * (1024 * 256);

    f32x4 acc[8];
    #pragma unroll
    for (int i = 0; i < 8; ++i) acc[i] = (f32x4){0, 0, 0, 0};

    uint4  g[2][4];     // prefetched corner gathers (double-buffered regs)
    float4 gw[2];       // matching bilinear weights

    // prologue: issue gathers for stage 0 (t=0)
    {
        gw[0] = sdw[pos];
        const int4 i4 = sdi[pos];
        const int cc = (kh * 2) * 64 + oct * 8;
        g[0][0] = *(const uint4*)(xn + i4.x + cc);
        g[0][1] = *(const uint4*)(xn + i4.y + cc);
        g[0][2] = *(const uint4*)(xn + i4.z + cc);
        g[0][3] = *(const uint4*)(xn + i4.w + cc);
    }

    #pragma unroll
    for (int s = 0; s < 18; ++s) {
        const int cur = s & 1, nxt = cur ^ 1;
        const int t = s % 9;
        const int cbase = (kh * 2 + s / 9) * 64;

        // ---- repack prefetched gathers -> LDS ---------------------------
        {
            const float4 w4 = gw[cur];
            const unsigned* p0 = (const unsigned*)&g[cur][0];
            const unsigned* p1 = (const unsigned*)&g[cur][1];
            const unsigned* p2 = (const unsigned*)&g[cur][2];
            const unsigned* p3 = (const unsigned*)&g[cur][3];
            union { s16x8 v; unsigned u[4]; } bu;
            #pragma unroll
            for (int d = 0; d < 4; ++d) {
                float lo = w4.x * bflo(p0[d]) + w4.y * bflo(p1[d])
                         + w4.z * bflo(p2[d]) + w4.w * bflo(p3[d]);
                float hi = w4.x * bfhi(p0[d]) + w4.y * bfhi(p1[d])
                         + w4.z * bfhi(p2[d]) + w4.w * bfhi(p3[d]);
                bu.u[d] = f2bf(lo) | (f2bf(hi) << 16);
            }
            *(s16x8*)&sB[cur][pos * 72 + oct * 8] = bu.v;
        }
        __syncthreads();

        // ---- A-frags (global, L2-resident), issued FIRST ----------------
        const short* ap = Wp + ((size_t)(t * 256 + oq * 64 + l15)) * 256
                             + cbase + quad * 8;
        s16x8 afr[4][2];
        #pragma unroll
        for (int mt = 0; mt < 4; ++mt)
            #pragma unroll
            for (int kc = 0; kc < 2; ++kc)
                afr[mt][kc] = *(const s16x8*)(ap + mt * 16 * 256 + kc * 32);

        // ---- issue gathers for stage s+1 (stay in flight across MFMAs) --
        if (s < 17) {
            const int t1 = (s + 1) % 9;
            const int cb1 = (kh * 2 + (s + 1) / 9) * 64;
            gw[nxt] = sdw[t1 * 32 + pos];
            const int4 i4 = sdi[t1 * 32 + pos];
            const int cc = cb1 + oct * 8;
            g[nxt][0] = *(const uint4*)(xn + i4.x + cc);
            g[nxt][1] = *(const uint4*)(xn + i4.y + cc);
            g[nxt][2] = *(const uint4*)(xn + i4.z + cc);
            g[nxt][3] = *(const uint4*)(xn + i4.w + cc);
        }

        // ---- B-frags + MFMA ---------------------------------------------
        s16x8 bfr[2][2];
        #pragma unroll
        for (int nt = 0; nt < 2; ++nt)
            #pragma unroll
            for (int kc = 0; kc < 2; ++kc)
                bfr[nt][kc] = *(const s16x8*)
                    &sB[cur][(nt * 16 + l15) * 72 + kc * 32 + quad * 8];

        #pragma unroll
        for (int mt = 0; mt < 4; ++mt)
            #pragma unroll
            for (int nt = 0; nt < 2; ++nt) {
                acc[mt * 2 + nt] = __builtin_amdgcn_mfma_f32_16x16x32_bf16(
                    afr[mt][0], bfr[nt][0], acc[mt * 2 + nt], 0, 0, 0);
                acc[mt * 2 + nt] = __builtin_amdgcn_mfma_f32_16x16x32_bf16(
                    afr[mt][1], bfr[nt][1], acc[mt * 2 + nt], 0, 0, 0);
            }
    }

    // ---- epilogue: atomic K-reduce onto bias-initialized out -------------
    const int bb = n >> 3, ts = n & 7;
    #pragma unroll
    for (int mt = 0; mt < 4; ++mt)
        #pragma unroll
        for (int nt = 0; nt < 2; ++nt)
            #pragma unroll
            for (int rr = 0; rr < 4; ++rr) {
                int oc = oq * 64 + mt * 16 + quad * 4 + rr;
                int p  = nt * 16 + l15;
                atomicAdd(out + (((size_t)bb * 256 + oc) * 8 + ts) * 1024
                              + ho * 32 + p,
                          acc[mt * 2 + nt][rr]);
            }
}

// ---------------------------------------------------------------------------
extern "C" void kernel_launch(void* const* d_in, const int* in_sizes, int n_in,
                              void* d_out, int out_size, void* d_ws, size_t ws_size,
                              hipStream_t stream) {
    const float* x        = (const float*)d_in[0];
    const float* weight   = (const float*)d_in[1];
    const float* bias     = (const float*)d_in[2];
    const float* offset_w = (const float*)d_in[3];
    const float* offset_b = (const float*)d_in[4];

    char* ws = (char*)d_ws;
    short*  xt    = (short*)ws;                       ws += (size_t)16 * 1024 * 256 * 2; // 8.39 MB
    short*  Wp    = (short*)ws;                       ws += (size_t)9 * 256 * 256 * 2;   // 1.18 MB
    short*  Wo    = (short*)ws;                       ws += (size_t)9 * 32 * 256 * 2;    // 147 KB
    float4* descW = (float4*)ws;                      ws += (size_t)147456 * 16;         // 2.36 MB
    int4*   descI = (int4*)ws;                        ws += (size_t)147456 * 16;         // 2.36 MB

    pack_x        <<<512,  256, 0, stream>>>(x, (unsigned*)xt);
    pack_wo       <<<2592, 256, 0, stream>>>(weight, offset_w, Wp, Wo);
    offsets_kernel<<<512,  256, 0, stream>>>(xt, Wo, offset_b, descW, descI);
    init_out      <<<4096, 256, 0, stream>>>(bias, (float4*)d_out);
    dcn_main      <<<1024, 256, 0, stream>>>(xt, Wp, descW, descI, (float*)d_out);
}

// Round 3
// 191.440 us; speedup vs baseline: 1.1973x; 1.0965x over previous
//
#include <hip/hip_runtime.h>
#include <math.h>

typedef __attribute__((ext_vector_type(4))) float f32x4;
typedef __attribute__((ext_vector_type(8))) short s16x8;

__device__ inline unsigned f2bf(float f) {
    unsigned u = __float_as_uint(f);
    u += 0x7FFFu + ((u >> 16) & 1u);
    return u >> 16;
}
__device__ inline float bflo(unsigned u) { return __uint_as_float(u << 16); }
__device__ inline float bfhi(unsigned u) { return __uint_as_float(u & 0xFFFF0000u); }

// ---------------------------------------------------------------------------
// pack_all: fused pack_x (blocks 0..511) + pack_wo (blocks 512..3103).
// pack_x: x (2,256,8,32,32) f32 -> xt[n][y][x][c] bf16 channels-last.
// pack_wo: weight -> Wp[t][o][c] bf16 ; offset_w -> Wo[t][m(pad32)][c] bf16.
// ---------------------------------------------------------------------------
__global__ __launch_bounds__(256) void pack_all(const float* __restrict__ x,
                                                const float* __restrict__ w,
                                                const float* __restrict__ ow,
                                                unsigned* __restrict__ xt32,
                                                short* __restrict__ Wp,
                                                short* __restrict__ Wo)
{
    __shared__ float tile[256][33];
    const int tid = threadIdx.x;
    if (blockIdx.x < 512) {
        const int n = blockIdx.x >> 5, y = blockIdx.x & 31;
        const int b = n >> 3, ts = n & 7;
        const float* src = x + (((size_t)b * 256 * 8) + ts) * 1024 + y * 32;
        #pragma unroll
        for (int rep = 0; rep < 32; ++rep) {
            int c = rep * 8 + (tid >> 5);
            int ww = tid & 31;
            tile[c][ww] = src[(size_t)c * 8192 + ww];
        }
        __syncthreads();
        unsigned* dst = xt32 + ((size_t)n * 1024 + y * 32) * 128;
        #pragma unroll
        for (int rep = 0; rep < 16; ++rep) {
            int idx = rep * 256 + tid;
            int cp = idx & 127, ww = idx >> 7;
            unsigned lo = f2bf(tile[2 * cp][ww]);
            unsigned hi = f2bf(tile[2 * cp + 1][ww]);
            dst[(size_t)ww * 128 + cp] = lo | (hi << 16);
        }
    } else {
        int j = (blockIdx.x - 512) * 256 + tid;
        if (j < 9 * 256 * 256) {
            int c = j & 255, o = (j >> 8) & 255, t = j >> 16;
            Wp[j] = (short)f2bf(w[((size_t)o * 256 + c) * 9 + t]);
        } else {
            int k = j - 9 * 256 * 256;            // < 9*32*256
            int c = k & 255, m = (k >> 8) & 31, t = k >> 13;
            float v = 0.f;
            if (m < 27) v = ow[((size_t)m * 256 + c) * 9 + t];
            Wo[k] = (short)f2bf(v);
        }
    }
}

// ---------------------------------------------------------------------------
// offsets_kernel: MFMA offset-conv + descriptor math -> global descW/descI.
// Block = (n, ho), 4 waves: nt = w&1, half = w>>1 (K-half).
// ---------------------------------------------------------------------------
__global__ __launch_bounds__(256) void offsets_kernel(
    const short* __restrict__ xt, const short* __restrict__ Wo,
    const float* __restrict__ ob, float4* __restrict__ descW,
    int4* __restrict__ descI)
{
    __shared__ float pom[2][32][33];
    const int tid = threadIdx.x;
    const int n = blockIdx.x >> 5, ho = blockIdx.x & 31;
    const int lane = tid & 63, wv = tid >> 6;
    const int nt = wv & 1, half = wv >> 1;
    const int l15 = lane & 15, quad = lane >> 4;
    const int pos = nt * 16 + l15;
    const short* xn = xt + (size_t)n * (1024 * 256);
    const s16x8 z8 = {0, 0, 0, 0, 0, 0, 0, 0};

    f32x4 oacc0 = {0, 0, 0, 0}, oacc1 = {0, 0, 0, 0};
    for (int t = 0; t < 9; ++t) {
        int ki = t / 3, kj = t - 3 * ki;
        int y = ho - 1 + ki;
        if (y < 0 || y >= 32) continue;
        int xc = pos - 1 + kj;
        bool vx = (xc >= 0) && (xc < 32);
        int xcl = min(max(xc, 0), 31);
        const short* bp  = xn + (y * 32 + xcl) * 256;
        const short* ap0 = Wo + (t * 32 + l15) * 256;
        #pragma unroll
        for (int cc = 0; cc < 4; ++cc) {
            int c = half * 128 + cc * 32 + quad * 8;
            s16x8 bfrag = *(const s16x8*)(bp + c);
            if (!vx) bfrag = z8;
            s16x8 a0 = *(const s16x8*)(ap0 + c);
            s16x8 a1 = *(const s16x8*)(ap0 + 16 * 256 + c);
            oacc0 = __builtin_amdgcn_mfma_f32_16x16x32_bf16(a0, bfrag, oacc0, 0, 0, 0);
            oacc1 = __builtin_amdgcn_mfma_f32_16x16x32_bf16(a1, bfrag, oacc1, 0, 0, 0);
        }
    }
    #pragma unroll
    for (int r = 0; r < 4; ++r) {
        pom[half][quad * 4 + r][pos]      = oacc0[r];
        pom[half][16 + quad * 4 + r][pos] = oacc1[r];
    }
    __syncthreads();

    for (int s = tid; s < 288; s += 256) {
        int t = s >> 5, wo = s & 31;
        float dy = pom[0][2 * t][wo]     + pom[1][2 * t][wo]     + ob[2 * t];
        float dx = pom[0][2 * t + 1][wo] + pom[1][2 * t + 1][wo] + ob[2 * t + 1];
        float mv = pom[0][18 + t][wo]    + pom[1][18 + t][wo]    + ob[18 + t];
        float mk = 1.0f / (1.0f + __expf(-mv));
        float py = dy + (float)(ho - 1 + t / 3);
        float px = dx + (float)(wo - 1 + t % 3);
        float y0f = floorf(py), x0f = floorf(px);
        float ty = py - y0f, tx = px - x0f;
        int y0 = (int)y0f, x0 = (int)x0f;
        int y1 = y0 + 1, x1 = x0 + 1;
        bool vy0 = (y0 >= 0) && (y0 < 32), vy1 = (y1 >= 0) && (y1 < 32);
        bool vx0 = (x0 >= 0) && (x0 < 32), vx1 = (x1 >= 0) && (x1 < 32);
        int cy0 = min(max(y0, 0), 31), cy1 = min(max(y1, 0), 31);
        int cx0 = min(max(x0, 0), 31), cx1 = min(max(x1, 0), 31);
        float b0 = (1.f - ty) * (1.f - tx) * mk * (float)(vy0 && vx0);
        float b1 = (1.f - ty) * tx         * mk * (float)(vy0 && vx1);
        float b2 = ty * (1.f - tx)         * mk * (float)(vy1 && vx0);
        float b3 = ty * tx                 * mk * (float)(vy1 && vx1);
        size_t base = (size_t)(n * 32 + ho) * 288 + s;
        descW[base] = make_float4(b0, b1, b2, b3);
        descI[base] = make_int4((cy0 * 32 + cx0) * 256, (cy0 * 32 + cx1) * 256,
                                (cy1 * 32 + cx0) * 256, (cy1 * 32 + cx1) * 256);
    }
}

// ---------------------------------------------------------------------------
// dcn_main: block = (n, ho, kh). 4 waves = oc-quarters, each does both
// n-tiles (A-frag reuse). 18 stages of (64 ch, 1 tap).
// Round-3 fix: the stage fence is ONE volatile asm "s_waitcnt lgkmcnt(0);
// s_barrier" with memory clobber. Round 2 split these into asm + builtin;
// llvm.amdgcn.s.barrier is IntrNoMem, so post-barrier ds_reads could be
// scheduled between the wait and the barrier -> read other waves' slices
// before they were written (intermittent post-timing divergence). Fusing
// them into one asm makes hoisting loads above the barrier impossible.
// vmcnt deliberately NOT drained at the fence: A-frags + next-stage gathers
// stay in flight across it (counted vmcnt at their uses).
// ---------------------------------------------------------------------------
__global__ __launch_bounds__(256, 4) void dcn_main(
    const short* __restrict__ xt, const short* __restrict__ Wp,
    const float4* __restrict__ descW, const int4* __restrict__ descI,
    const float* __restrict__ bias, float* __restrict__ out,
    float* __restrict__ ws1)
{
    __shared__ short  sB[2][32 * 72];    // 32 pos x 64 c (+8 pad), 16B rows
    __shared__ float4 sdw[288];
    __shared__ int4   sdi[288];

    const int tid = threadIdx.x;
    const int bid = blockIdx.x;
    const int kh = bid & 1;
    const int r  = bid >> 1;
    const int n = r >> 5, ho = r & 31;

    // stage descriptors for this (n, ho)
    {
        const float4* dW = descW + (size_t)(n * 32 + ho) * 288;
        const int4*   dI = descI + (size_t)(n * 32 + ho) * 288;
        for (int i = tid; i < 288; i += 256) { sdw[i] = dW[i]; sdi[i] = dI[i]; }
    }
    __syncthreads();

    const int oct = tid & 7, pos = tid >> 3;       // coalesced repack role
    const int oq = tid >> 6;                       // wave = oc-quarter
    const int lane = tid & 63, l15 = lane & 15, quad = lane >> 4;
    const short* xn = xt + (size_t)n * (1024 * 256);

    f32x4 acc[8];
    #pragma unroll
    for (int i = 0; i < 8; ++i) acc[i] = (f32x4){0, 0, 0, 0};

    uint4  g[2][4];     // prefetched corner gathers (double-buffered regs)
    float4 gw[2];       // matching bilinear weights

    // prologue: issue gathers for stage 0 (t=0)
    {
        gw[0] = sdw[pos];
        const int4 i4 = sdi[pos];
        const int cc = (kh * 2) * 64 + oct * 8;
        g[0][0] = *(const uint4*)(xn + i4.x + cc);
        g[0][1] = *(const uint4*)(xn + i4.y + cc);
        g[0][2] = *(const uint4*)(xn + i4.z + cc);
        g[0][3] = *(const uint4*)(xn + i4.w + cc);
    }

    #pragma unroll
    for (int s = 0; s < 18; ++s) {
        const int cur = s & 1, nxt = cur ^ 1;
        const int t = s % 9;
        const int cbase = (kh * 2 + s / 9) * 64;

        // ---- A-frags issued FIRST: latency hides under repack ------------
        const short* ap = Wp + ((size_t)(t * 256 + oq * 64 + l15)) * 256
                             + cbase + quad * 8;
        s16x8 afr[4][2];
        #pragma unroll
        for (int mt = 0; mt < 4; ++mt)
            #pragma unroll
            for (int kc = 0; kc < 2; ++kc)
                afr[mt][kc] = *(const s16x8*)(ap + mt * 16 * 256 + kc * 32);

        // ---- repack prefetched gathers -> LDS ---------------------------
        {
            const float4 w4 = gw[cur];
            const unsigned* p0 = (const unsigned*)&g[cur][0];
            const unsigned* p1 = (const unsigned*)&g[cur][1];
            const unsigned* p2 = (const unsigned*)&g[cur][2];
            const unsigned* p3 = (const unsigned*)&g[cur][3];
            union { s16x8 v; unsigned u[4]; } bu;
            #pragma unroll
            for (int d = 0; d < 4; ++d) {
                float lo = w4.x * bflo(p0[d]) + w4.y * bflo(p1[d])
                         + w4.z * bflo(p2[d]) + w4.w * bflo(p3[d]);
                float hi = w4.x * bfhi(p0[d]) + w4.y * bfhi(p1[d])
                         + w4.z * bfhi(p2[d]) + w4.w * bfhi(p3[d]);
                bu.u[d] = f2bf(lo) | (f2bf(hi) << 16);
            }
            *(s16x8*)&sB[cur][pos * 72 + oct * 8] = bu.v;
        }

        // Fused LDS-drain + barrier (single asm: nothing can be scheduled
        // between the wait and the barrier). vmcnt stays in flight.
        asm volatile("s_waitcnt lgkmcnt(0)\n\ts_barrier" ::: "memory");
        __builtin_amdgcn_sched_barrier(0);

        // ---- issue gathers for stage s+1 (stay in flight across MFMAs) --
        if (s < 17) {
            const int t1 = (s + 1) % 9;
            const int cb1 = (kh * 2 + (s + 1) / 9) * 64;
            gw[nxt] = sdw[t1 * 32 + pos];
            const int4 i4 = sdi[t1 * 32 + pos];
            const int cc = cb1 + oct * 8;
            g[nxt][0] = *(const uint4*)(xn + i4.x + cc);
            g[nxt][1] = *(const uint4*)(xn + i4.y + cc);
            g[nxt][2] = *(const uint4*)(xn + i4.z + cc);
            g[nxt][3] = *(const uint4*)(xn + i4.w + cc);
        }

        // ---- B-frags + MFMA ---------------------------------------------
        s16x8 bfr[2][2];
        #pragma unroll
        for (int nt = 0; nt < 2; ++nt)
            #pragma unroll
            for (int kc = 0; kc < 2; ++kc)
                bfr[nt][kc] = *(const s16x8*)
                    &sB[cur][(nt * 16 + l15) * 72 + kc * 32 + quad * 8];

        #pragma unroll
        for (int mt = 0; mt < 4; ++mt)
            #pragma unroll
            for (int nt = 0; nt < 2; ++nt) {
                acc[mt * 2 + nt] = __builtin_amdgcn_mfma_f32_16x16x32_bf16(
                    afr[mt][0], bfr[nt][0], acc[mt * 2 + nt], 0, 0, 0);
                acc[mt * 2 + nt] = __builtin_amdgcn_mfma_f32_16x16x32_bf16(
                    afr[mt][1], bfr[nt][1], acc[mt * 2 + nt], 0, 0, 0);
            }
    }

    // ---- epilogue: plain coalesced stores (no atomics) -------------------
    const int bb = n >> 3, ts = n & 7;
    if (kh == 0) {
        #pragma unroll
        for (int mt = 0; mt < 4; ++mt) {
            const float4 bv = *(const float4*)(bias + oq * 64 + mt * 16 + quad * 4);
            #pragma unroll
            for (int nt = 0; nt < 2; ++nt)
                #pragma unroll
                for (int rr = 0; rr < 4; ++rr) {
                    int oc = oq * 64 + mt * 16 + quad * 4 + rr;
                    int p  = nt * 16 + l15;
                    out[(((size_t)bb * 256 + oc) * 8 + ts) * 1024 + ho * 32 + p] =
                        acc[mt * 2 + nt][rr] + ((const float*)&bv)[rr];
                }
        }
    } else {
        float* wp1 = ws1 + (size_t)(n * 32 + ho) * 256 * 32;
        #pragma unroll
        for (int mt = 0; mt < 4; ++mt)
            #pragma unroll
            for (int nt = 0; nt < 2; ++nt)
                #pragma unroll
                for (int rr = 0; rr < 4; ++rr) {
                    int oc = oq * 64 + mt * 16 + quad * 4 + rr;
                    int p  = nt * 16 + l15;
                    wp1[oc * 32 + p] = acc[mt * 2 + nt][rr];
                }
    }
}

// ---------------------------------------------------------------------------
// reduce_out: out += ws1 (kh=1 partial). Fully BW-bound. 4096 blocks.
// ---------------------------------------------------------------------------
__global__ __launch_bounds__(256) void reduce_out(const float* __restrict__ ws1,
                                                  float4* __restrict__ out)
{
    int i = blockIdx.x * 256 + threadIdx.x;   // < 1048576 float4s
    int f = i * 4;
    int p  = f & 1023;             // ho*32 + pp
    int ts = (f >> 10) & 7;
    int oc = (f >> 13) & 255;
    int bb = f >> 21;
    int n = bb * 8 + ts;
    int ho = p >> 5, pp = p & 31;
    const float4 w = *(const float4*)(ws1 + ((size_t)(n * 32 + ho) * 256 + oc) * 32 + pp);
    float4 a = out[i];
    a.x += w.x; a.y += w.y; a.z += w.z; a.w += w.w;
    out[i] = a;
}

// ---------------------------------------------------------------------------
extern "C" void kernel_launch(void* const* d_in, const int* in_sizes, int n_in,
                              void* d_out, int out_size, void* d_ws, size_t ws_size,
                              hipStream_t stream) {
    const float* x        = (const float*)d_in[0];
    const float* weight   = (const float*)d_in[1];
    const float* bias     = (const float*)d_in[2];
    const float* offset_w = (const float*)d_in[3];
    const float* offset_b = (const float*)d_in[4];

    char* ws = (char*)d_ws;
    short*  xt    = (short*)ws;                       ws += (size_t)16 * 1024 * 256 * 2; // 8.39 MB
    short*  Wp    = (short*)ws;                       ws += (size_t)9 * 256 * 256 * 2;   // 1.18 MB
    short*  Wo    = (short*)ws;                       ws += (size_t)9 * 32 * 256 * 2;    // 147 KB
    float4* descW = (float4*)ws;                      ws += (size_t)147456 * 16;         // 2.36 MB
    int4*   descI = (int4*)ws;                        ws += (size_t)147456 * 16;         // 2.36 MB
    float*  ws1   = (float*)ws;                       ws += (size_t)16 * 32 * 256 * 32 * 4; // 16.8 MB

    pack_all      <<<3104, 256, 0, stream>>>(x, weight, offset_w, (unsigned*)xt, Wp, Wo);
    offsets_kernel<<<512,  256, 0, stream>>>(xt, Wo, offset_b, descW, descI);
    dcn_main      <<<1024, 256, 0, stream>>>(xt, Wp, descW, descI, bias, (float*)d_out, ws1);
    reduce_out    <<<4096, 256, 0, stream>>>(ws1, (float4*)d_out);
}